// Round 15
// baseline (424.132 us; speedup 1.0000x reference)
//
#include <hip/hip_runtime.h>
#include <math.h>

#define NN_ 40000
#define NE_ 640000
#define NG_ 400
#define NBLK_SCAN 157    // ceil(40000/256)
#define NBP 1024         // stage-1 partial blocks for BN stats (atomic-free)
#define NB2 32           // stage-2 reduced partials

typedef unsigned short ushort_t;
typedef __attribute__((ext_vector_type(8))) short bf16x8;
typedef __attribute__((ext_vector_type(4))) float f32x4;

// ---------------- device scratch ----------------
// NOTE: __device__ globals must NEVER be passed as kernel arguments from host
// (host sees shadow symbol address -> GPU fault). Always bind inside kernels.
__device__ int    g_deg[NN_];        // zero at load (BSS); re-zeroed by k_scan3 each launch
__device__ int    g_rowstart[NN_ + 1];
__device__ int    g_cursor[NN_];
__device__ int    g_srccsr[NE_];
__device__ float4 g_eacsr[NE_];
__device__ int    g_bsum[NBLK_SCAN], g_boff[NBLK_SCAN];
__device__ ushort_t g_xl2[(size_t)NN_ * 256];
__device__ ushort_t g_xr2[(size_t)NN_ * 256];
__device__ float  g_h1[(size_t)NN_ * 256];
__device__ ushort_t g_h1b[(size_t)NN_ * 256];   // bf16 h1 (post BN+ELU) for MFMA GEMM
__device__ ushort_t g_wl2t[256 * 256];          // Wl2^T bf16 [n][k]
__device__ ushort_t g_wr2t[256 * 256];          // Wr2^T bf16 [n][k]
__device__ float  g_h2[(size_t)NN_ * 128];      // raw (pre-BN) layer-2 output
__device__ float  g_part_s[NBP][256];           // BN stage-1 partials
__device__ float  g_part_q[NBP][256];
__device__ float  g_p2_s[NB2][256];             // BN stage-2 partials
__device__ float  g_p2_q[NB2][256];
__device__ float  g_scale[256], g_shift[256];

// bf16 helpers: arrays of ushort bf16, accessed pairwise via uint
__device__ __forceinline__ float bflo(unsigned int q) { return __uint_as_float(q << 16); }
__device__ __forceinline__ float bfhi(unsigned int q) { return __uint_as_float(q & 0xFFFF0000u); }
__device__ __forceinline__ unsigned int f2bf(float f) {
    unsigned int u = __float_as_uint(f);
    return (u + 0x7FFFu + ((u >> 16) & 1u)) >> 16;
}
__device__ __forceinline__ unsigned int pack2(float a, float b) {
    return f2bf(a) | (f2bf(b) << 16);
}

// ---------------- CSR build ----------------
__global__ void k_hist(const int* __restrict__ dst) {
    int e = blockIdx.x * blockDim.x + threadIdx.x;
    if (e < NE_) atomicAdd(&g_deg[dst[e]], 1);
}

__global__ void k_scan1() {
    __shared__ int sd[256];
    int b = blockIdx.x, t = threadIdx.x, i = b * 256 + t;
    int v = (i < NN_) ? g_deg[i] : 0;
    sd[t] = v;
    __syncthreads();
    for (int off = 1; off < 256; off <<= 1) {
        int tv = (t >= off) ? sd[t - off] : 0;
        __syncthreads();
        sd[t] += tv;
        __syncthreads();
    }
    if (i < NN_) g_rowstart[i] = sd[t] - v;   // block-local exclusive
    if (t == 255) g_bsum[b] = sd[255];
}

__global__ void k_scan2() {
    __shared__ int sd[256];
    int t = threadIdx.x;
    int v = (t < NBLK_SCAN) ? g_bsum[t] : 0;
    sd[t] = v;
    __syncthreads();
    for (int off = 1; off < 256; off <<= 1) {
        int tv = (t >= off) ? sd[t - off] : 0;
        __syncthreads();
        sd[t] += tv;
        __syncthreads();
    }
    if (t < NBLK_SCAN) g_boff[t] = sd[t] - v;
    if (t == 255) g_rowstart[NN_] = sd[255];
}

__global__ void k_scan3() {
    int i = blockIdx.x * blockDim.x + threadIdx.x;
    if (i < NN_) {
        int r = g_rowstart[i] + g_boff[i >> 8];
        g_rowstart[i] = r;
        g_cursor[i] = r;
        g_deg[i] = 0;   // restore invariant for next launch (k_scan1 already consumed)
    }
}

__global__ void k_scatter(const int* __restrict__ src, const int* __restrict__ dst,
                          const float* __restrict__ ea) {
    int e = blockIdx.x * blockDim.x + threadIdx.x;
    if (e < NE_) {
        int pos = atomicAdd(&g_cursor[dst[e]], 1);
        g_srccsr[pos] = src[e];
        g_eacsr[pos] = reinterpret_cast<const float4*>(ea)[e];
    }
}

// ---------------- fused GATv2 layer: flash-style, ONE WAVE (64 thr) per node ----
// Unroll-2 with MERGED online-softmax update (exact): one max/ballot/rescale per
// edge pair; both logit reduce chains computed independently (ILP). No explicit
// software pipeline -- TLP at ~70% occupancy hides load latency, and dropping
// the pipeline removes the per-edge register-swap movs.
template <int LAYER>
__global__ void k_gat(const float* __restrict__ att, const float* __restrict__ We,
                      const float* __restrict__ bias, const float* __restrict__ x,
                      const float* __restrict__ Wl, const float* __restrict__ bl,
                      const float* __restrict__ Wr, const float* __restrict__ br) {
    constexpr int C = (LAYER == 1) ? 64 : 128;    // channels per head
    constexpr int GL = C / 4;                     // lanes per head group
    float* __restrict__ hout = (LAYER == 1) ? g_h1 : g_h2;

    int lane = threadIdx.x;      // 64 threads = 1 wave
    int n = blockIdx.x;
    int c4 = lane * 4;

    float a0 = att[c4], a1 = att[c4 + 1], a2c = att[c4 + 2], a3 = att[c4 + 3];
    float we00 = We[c4], we01 = We[c4 + 1], we02 = We[c4 + 2], we03 = We[c4 + 3];
    float we10 = We[256 + c4], we11 = We[256 + c4 + 1], we12 = We[256 + c4 + 2], we13 = We[256 + c4 + 3];
    float we20 = We[512 + c4], we21 = We[512 + c4 + 1], we22 = We[512 + c4 + 2], we23 = We[512 + c4 + 3];
    float we30 = We[768 + c4], we31 = We[768 + c4 + 1], we32 = We[768 + c4 + 2], we33 = We[768 + c4 + 3];

    // layer-1 source-transform columns (held in registers)
    float wl00 = 0.f, wl01 = 0.f, wl02 = 0.f, wl03 = 0.f;
    float wl10 = 0.f, wl11 = 0.f, wl12 = 0.f, wl13 = 0.f;
    float bl0 = 0.f, bl1 = 0.f, bl2 = 0.f, bl3 = 0.f;
    float xr0, xr1, xr2, xr3;
    if constexpr (LAYER == 1) {
        wl00 = Wl[c4 + 0]; wl01 = Wl[c4 + 1]; wl02 = Wl[c4 + 2]; wl03 = Wl[c4 + 3];
        wl10 = Wl[256 + c4 + 0]; wl11 = Wl[256 + c4 + 1]; wl12 = Wl[256 + c4 + 2]; wl13 = Wl[256 + c4 + 3];
        bl0 = bl[c4 + 0]; bl1 = bl[c4 + 1]; bl2 = bl[c4 + 2]; bl3 = bl[c4 + 3];
        float2 xn = *reinterpret_cast<const float2*>(x + 2 * n);
        xr0 = xn.x * Wr[c4 + 0] + xn.y * Wr[256 + c4 + 0] + br[c4 + 0];
        xr1 = xn.x * Wr[c4 + 1] + xn.y * Wr[256 + c4 + 1] + br[c4 + 1];
        xr2 = xn.x * Wr[c4 + 2] + xn.y * Wr[256 + c4 + 2] + br[c4 + 2];
        xr3 = xn.x * Wr[c4 + 3] + xn.y * Wr[256 + c4 + 3] + br[c4 + 3];
    } else {
        uint2 xq = *reinterpret_cast<const uint2*>(g_xr2 + (size_t)n * 256 + c4);
        xr0 = bflo(xq.x); xr1 = bfhi(xq.x); xr2 = bflo(xq.y); xr3 = bfhi(xq.y);
    }

    int s0 = g_rowstart[n];
    int d = g_rowstart[n + 1] - s0;

    float mrun = -INFINITY, den = 0.f;
    float acc0 = 0.f, acc1 = 0.f, acc2 = 0.f, acc3 = 0.f;

    int i = 0;
    for (; i + 1 < d; i += 2) {
        int sA = g_srccsr[s0 + i];
        int sB = g_srccsr[s0 + i + 1];
        float4 eaA = g_eacsr[s0 + i];
        float4 eaB = g_eacsr[s0 + i + 1];
        float xa0, xa1, xa2, xa3, xb0, xb1, xb2, xb3;
        if constexpr (LAYER == 1) {
            float2 xsA = *reinterpret_cast<const float2*>(x + 2 * sA);
            float2 xsB = *reinterpret_cast<const float2*>(x + 2 * sB);
            xa0 = fmaf(xsA.y, wl10, fmaf(xsA.x, wl00, bl0));
            xa1 = fmaf(xsA.y, wl11, fmaf(xsA.x, wl01, bl1));
            xa2 = fmaf(xsA.y, wl12, fmaf(xsA.x, wl02, bl2));
            xa3 = fmaf(xsA.y, wl13, fmaf(xsA.x, wl03, bl3));
            xb0 = fmaf(xsB.y, wl10, fmaf(xsB.x, wl00, bl0));
            xb1 = fmaf(xsB.y, wl11, fmaf(xsB.x, wl01, bl1));
            xb2 = fmaf(xsB.y, wl12, fmaf(xsB.x, wl02, bl2));
            xb3 = fmaf(xsB.y, wl13, fmaf(xsB.x, wl03, bl3));
        } else {
            uint2 rA = *reinterpret_cast<const uint2*>(g_xl2 + (size_t)sA * 256 + c4);
            uint2 rB = *reinterpret_cast<const uint2*>(g_xl2 + (size_t)sB * 256 + c4);
            xa0 = bflo(rA.x); xa1 = bfhi(rA.x); xa2 = bflo(rA.y); xa3 = bfhi(rA.y);
            xb0 = bflo(rB.x); xb1 = bfhi(rB.x); xb2 = bflo(rB.y); xb3 = bfhi(rB.y);
        }
        float z0 = xa0 + xr0 + eaA.x * we00 + eaA.y * we10 + eaA.z * we20 + eaA.w * we30;
        float z1 = xa1 + xr1 + eaA.x * we01 + eaA.y * we11 + eaA.z * we21 + eaA.w * we31;
        float z2 = xa2 + xr2 + eaA.x * we02 + eaA.y * we12 + eaA.z * we22 + eaA.w * we32;
        float z3 = xa3 + xr3 + eaA.x * we03 + eaA.y * we13 + eaA.z * we23 + eaA.w * we33;
        float y0 = xb0 + xr0 + eaB.x * we00 + eaB.y * we10 + eaB.z * we20 + eaB.w * we30;
        float y1 = xb1 + xr1 + eaB.x * we01 + eaB.y * we11 + eaB.z * we21 + eaB.w * we31;
        float y2 = xb2 + xr2 + eaB.x * we02 + eaB.y * we12 + eaB.z * we22 + eaB.w * we32;
        float y3 = xb3 + xr3 + eaB.x * we03 + eaB.y * we13 + eaB.z * we23 + eaB.w * we33;
        z0 = fmaxf(z0, 0.2f * z0); z1 = fmaxf(z1, 0.2f * z1);
        z2 = fmaxf(z2, 0.2f * z2); z3 = fmaxf(z3, 0.2f * z3);
        y0 = fmaxf(y0, 0.2f * y0); y1 = fmaxf(y1, 0.2f * y1);
        y2 = fmaxf(y2, 0.2f * y2); y3 = fmaxf(y3, 0.2f * y3);
        float t0 = z0 * a0 + z1 * a1 + z2 * a2c + z3 * a3;
        float t1 = y0 * a0 + y1 * a1 + y2 * a2c + y3 * a3;
#pragma unroll
        for (int off = 1; off < GL; off <<= 1) {
            t0 += __shfl_xor(t0, off);
            t1 += __shfl_xor(t1, off);
        }
        float tm = fmaxf(t0, t1);
        if (__ballot(tm > mrun) == 0ULL) {
            // fast path (exact): no new max anywhere in the wave
            float w0 = __expf(t0 - mrun), w1 = __expf(t1 - mrun);
            den += w0 + w1;
            acc0 = fmaf(w1, xb0, fmaf(w0, xa0, acc0));
            acc1 = fmaf(w1, xb1, fmaf(w0, xa1, acc1));
            acc2 = fmaf(w1, xb2, fmaf(w0, xa2, acc2));
            acc3 = fmaf(w1, xb3, fmaf(w0, xa3, acc3));
        } else {
            float mnew = fmaxf(mrun, tm);
            float scl = __expf(mrun - mnew);
            float w0 = __expf(t0 - mnew), w1 = __expf(t1 - mnew);
            den = fmaf(den, scl, w0 + w1);
            acc0 = fmaf(w1, xb0, fmaf(w0, xa0, acc0 * scl));
            acc1 = fmaf(w1, xb1, fmaf(w0, xa1, acc1 * scl));
            acc2 = fmaf(w1, xb2, fmaf(w0, xa2, acc2 * scl));
            acc3 = fmaf(w1, xb3, fmaf(w0, xa3, acc3 * scl));
            mrun = mnew;
        }
    }
    if (i < d) {   // odd-degree tail edge
        int sA = g_srccsr[s0 + i];
        float4 eaA = g_eacsr[s0 + i];
        float xa0, xa1, xa2, xa3;
        if constexpr (LAYER == 1) {
            float2 xsA = *reinterpret_cast<const float2*>(x + 2 * sA);
            xa0 = fmaf(xsA.y, wl10, fmaf(xsA.x, wl00, bl0));
            xa1 = fmaf(xsA.y, wl11, fmaf(xsA.x, wl01, bl1));
            xa2 = fmaf(xsA.y, wl12, fmaf(xsA.x, wl02, bl2));
            xa3 = fmaf(xsA.y, wl13, fmaf(xsA.x, wl03, bl3));
        } else {
            uint2 rA = *reinterpret_cast<const uint2*>(g_xl2 + (size_t)sA * 256 + c4);
            xa0 = bflo(rA.x); xa1 = bfhi(rA.x); xa2 = bflo(rA.y); xa3 = bfhi(rA.y);
        }
        float z0 = xa0 + xr0 + eaA.x * we00 + eaA.y * we10 + eaA.z * we20 + eaA.w * we30;
        float z1 = xa1 + xr1 + eaA.x * we01 + eaA.y * we11 + eaA.z * we21 + eaA.w * we31;
        float z2 = xa2 + xr2 + eaA.x * we02 + eaA.y * we12 + eaA.z * we22 + eaA.w * we32;
        float z3 = xa3 + xr3 + eaA.x * we03 + eaA.y * we13 + eaA.z * we23 + eaA.w * we33;
        z0 = fmaxf(z0, 0.2f * z0); z1 = fmaxf(z1, 0.2f * z1);
        z2 = fmaxf(z2, 0.2f * z2); z3 = fmaxf(z3, 0.2f * z3);
        float t0 = z0 * a0 + z1 * a1 + z2 * a2c + z3 * a3;
#pragma unroll
        for (int off = 1; off < GL; off <<= 1) t0 += __shfl_xor(t0, off);
        if (__ballot(t0 > mrun) == 0ULL) {
            float w = __expf(t0 - mrun);
            den += w;
            acc0 = fmaf(w, xa0, acc0);
            acc1 = fmaf(w, xa1, acc1);
            acc2 = fmaf(w, xa2, acc2);
            acc3 = fmaf(w, xa3, acc3);
        } else {
            float mnew = fmaxf(mrun, t0);
            float scl = __expf(mrun - mnew);
            float w = __expf(t0 - mnew);
            den = fmaf(den, scl, w);
            acc0 = fmaf(w, xa0, acc0 * scl);
            acc1 = fmaf(w, xa1, acc1 * scl);
            acc2 = fmaf(w, xa2, acc2 * scl);
            acc3 = fmaf(w, xa3, acc3 * scl);
            mrun = mnew;
        }
    }
    float inv = 1.f / (den + 1e-16f);
    if constexpr (LAYER == 1) {
        float4 o = make_float4(acc0 * inv + bias[c4 + 0], acc1 * inv + bias[c4 + 1],
                               acc2 * inv + bias[c4 + 2], acc3 * inv + bias[c4 + 3]);
        *reinterpret_cast<float4*>(hout + (size_t)n * 256 + c4) = o;
    } else {
        float v0 = acc0 * inv, v1 = acc1 * inv, v2 = acc2 * inv, v3 = acc3 * inv;
        float u0 = __shfl_xor(v0, 32), u1 = __shfl_xor(v1, 32);
        float u2 = __shfl_xor(v2, 32), u3 = __shfl_xor(v3, 32);
        if (lane < 32) {
            float4 o = make_float4(0.5f * (v0 + u0) + bias[c4 + 0],
                                   0.5f * (v1 + u1) + bias[c4 + 1],
                                   0.5f * (v2 + u2) + bias[c4 + 2],
                                   0.5f * (v3 + u3) + bias[c4 + 3]);
            *reinterpret_cast<float4*>(hout + (size_t)n * 128 + c4) = o;
        }
    }
}

// ---------------- batchnorm: atomic-free three-level reduction ----------------
template <int C>
__global__ void k_bn_stats() {
    const float* h = (C == 256) ? (const float*)g_h1 : (const float*)g_h2;
    int c = threadIdx.x;
    float s = 0.f, ss = 0.f;
    for (int r = blockIdx.x; r < NN_; r += NBP) {
        float v = h[(size_t)r * C + c];
        s += v; ss += v * v;
    }
    g_part_s[blockIdx.x][c] = s;
    g_part_q[blockIdx.x][c] = ss;
}

template <int C>
__global__ void k_bn_reduce() {
    int c = threadIdx.x;
    int b = blockIdx.x;
    float s = 0.f, ss = 0.f;
    for (int p = b; p < NBP; p += NB2) {
        s += g_part_s[p][c];
        ss += g_part_q[p][c];
    }
    g_p2_s[b][c] = s;
    g_p2_q[b][c] = ss;
}

template <int C>
__global__ void k_bn_finalize(const float* __restrict__ g, const float* __restrict__ b) {
    int c = threadIdx.x;
    float s = 0.f, ss = 0.f;
#pragma unroll
    for (int p = 0; p < NB2; ++p) {
        s += g_p2_s[p][c];
        ss += g_p2_q[p][c];
    }
    float mu = s / (float)NN_;
    float var = ss / (float)NN_ - mu * mu;
    float sc = g[c] * rsqrtf(var + 1e-5f);
    g_scale[c] = sc;
    g_shift[c] = b[c] - mu * sc;
}

// BN+ELU for layer1, emitting bf16 g_h1b (feeds MFMA GEMM); vectorized 8-wide
__global__ void k_bn_apply1() {
    int i = blockIdx.x * blockDim.x + threadIdx.x;
    int stride = gridDim.x * blockDim.x;
    for (int j8 = i; j8 < NN_ * 32; j8 += stride) {
        size_t base = (size_t)j8 * 8;
        int c0 = (int)(base & 255);
        float4 v0 = *reinterpret_cast<const float4*>(g_h1 + base);
        float4 v1 = *reinterpret_cast<const float4*>(g_h1 + base + 4);
        float e[8];
        e[0] = v0.x * g_scale[c0 + 0] + g_shift[c0 + 0];
        e[1] = v0.y * g_scale[c0 + 1] + g_shift[c0 + 1];
        e[2] = v0.z * g_scale[c0 + 2] + g_shift[c0 + 2];
        e[3] = v0.w * g_scale[c0 + 3] + g_shift[c0 + 3];
        e[4] = v1.x * g_scale[c0 + 4] + g_shift[c0 + 4];
        e[5] = v1.y * g_scale[c0 + 5] + g_shift[c0 + 5];
        e[6] = v1.z * g_scale[c0 + 6] + g_shift[c0 + 6];
        e[7] = v1.w * g_scale[c0 + 7] + g_shift[c0 + 7];
#pragma unroll
        for (int q = 0; q < 8; ++q) e[q] = e[q] > 0.f ? e[q] : expm1f(e[q]);
        uint4 o = make_uint4(pack2(e[0], e[1]), pack2(e[2], e[3]),
                             pack2(e[4], e[5]), pack2(e[6], e[7]));
        *reinterpret_cast<uint4*>(g_h1b + base) = o;
    }
}

// ---------------- weight convert+transpose: W[k][n] fp32 -> Wt[n][k] bf16 --------
__global__ void k_wconv(const float* __restrict__ Wl, const float* __restrict__ Wr) {
    int n = blockIdx.x, k = threadIdx.x;   // 256 x 256
    g_wl2t[n * 256 + k] = (ushort_t)f2bf(Wl[(size_t)k * 256 + n]);
    g_wr2t[n * 256 + k] = (ushort_t)f2bf(Wr[(size_t)k * 256 + n]);
}

// ---------------- MFMA dual GEMM: h1b(40000x256,bf16) @ {Wl2,Wr2} -> xl2/xr2 ----
__global__ __launch_bounds__(256) void k_gemm2(const float* __restrict__ bl,
                                               const float* __restrict__ br) {
    __shared__ ushort_t As[128][40];
    __shared__ ushort_t Bs[2][64][40];
    int tid = threadIdx.x;
    int w = tid >> 6, lane = tid & 63;
    int m0 = blockIdx.x * 128, n0 = blockIdx.y * 64;

    f32x4 acc[2][4][2] = {};

    for (int k0 = 0; k0 < 256; k0 += 32) {
#pragma unroll
        for (int c = tid; c < 512; c += 256) {
            int row = c >> 2, seg = c & 3;
            int gr = m0 + row; gr = gr < NN_ ? gr : NN_ - 1;
            uint4 v = *reinterpret_cast<const uint4*>(g_h1b + (size_t)gr * 256 + k0 + seg * 8);
            *reinterpret_cast<uint4*>(&As[row][seg * 8]) = v;
        }
        {
            int row = tid >> 2, seg = tid & 3;
            uint4 v0 = *reinterpret_cast<const uint4*>(g_wl2t + (size_t)(n0 + row) * 256 + k0 + seg * 8);
            *reinterpret_cast<uint4*>(&Bs[0][row][seg * 8]) = v0;
            uint4 v1 = *reinterpret_cast<const uint4*>(g_wr2t + (size_t)(n0 + row) * 256 + k0 + seg * 8);
            *reinterpret_cast<uint4*>(&Bs[1][row][seg * 8]) = v1;
        }
        __syncthreads();
        int kb = (lane >> 4) * 8;
        bf16x8 a0 = *reinterpret_cast<const bf16x8*>(&As[w * 32 + (lane & 15)][kb]);
        bf16x8 a1 = *reinterpret_cast<const bf16x8*>(&As[w * 32 + 16 + (lane & 15)][kb]);
        bf16x8 b[4][2];
#pragma unroll
        for (int ni = 0; ni < 4; ++ni) {
            b[ni][0] = *reinterpret_cast<const bf16x8*>(&Bs[0][ni * 16 + (lane & 15)][kb]);
            b[ni][1] = *reinterpret_cast<const bf16x8*>(&Bs[1][ni * 16 + (lane & 15)][kb]);
        }
#pragma unroll
        for (int ni = 0; ni < 4; ++ni) {
#pragma unroll
            for (int mat = 0; mat < 2; ++mat) {
                acc[0][ni][mat] = __builtin_amdgcn_mfma_f32_16x16x32_bf16(a0, b[ni][mat], acc[0][ni][mat], 0, 0, 0);
                acc[1][ni][mat] = __builtin_amdgcn_mfma_f32_16x16x32_bf16(a1, b[ni][mat], acc[1][ni][mat], 0, 0, 0);
            }
        }
        __syncthreads();
    }
#pragma unroll
    for (int mat = 0; mat < 2; ++mat) {
        const float* bb = mat ? br : bl;
        ushort_t* outp = mat ? g_xr2 : g_xl2;
#pragma unroll
        for (int ni = 0; ni < 4; ++ni) {
            int gcol = n0 + ni * 16 + (lane & 15);
            float bv = bb[gcol];
#pragma unroll
            for (int mi = 0; mi < 2; ++mi) {
#pragma unroll
                for (int r = 0; r < 4; ++r) {
                    int grow = m0 + w * 32 + mi * 16 + (lane >> 4) * 4 + r;
                    if (grow < NN_)
                        outp[(size_t)grow * 256 + gcol] = (ushort_t)f2bf(acc[mi][ni][mat][r] + bv);
                }
            }
        }
    }
}

// ---------------- fused tail: BN-finalize(128) + mean-pool(BN+ELU) + MLP head ----
__global__ void k_tail(const float* __restrict__ g2, const float* __restrict__ be2,
                       const int* __restrict__ batch,
                       const float* __restrict__ W1, const float* __restrict__ b1,
                       const float* __restrict__ W2, const float* __restrict__ b2,
                       float* __restrict__ out) {
    int g = blockIdx.x, t = threadIdx.x;  // 128 threads
    float s = 0.f, ss = 0.f;
#pragma unroll
    for (int p = 0; p < NB2; ++p) {
        s += g_p2_s[p][t];
        ss += g_p2_q[p][t];
    }
    float mu = s / (float)NN_;
    float var = ss / (float)NN_ - mu * mu;
    float sc = g2[t] * rsqrtf(var + 1e-5f);
    float sh = be2[t] - mu * sc;
    __shared__ int sbeg, send;
    if (t == 0) {
        int lo = 0, hi = NN_;
        while (lo < hi) { int mid = (lo + hi) >> 1; if (batch[mid] < g) lo = mid + 1; else hi = mid; }
        sbeg = lo;
    }
    if (t == 1) {
        int lo = 0, hi = NN_;
        while (lo < hi) { int mid = (lo + hi) >> 1; if (batch[mid] <= g) lo = mid + 1; else hi = mid; }
        send = lo;
    }
    __syncthreads();
    int beg = sbeg, end = send;
    float acc = 0.f;
    for (int n = beg; n < end; ++n) {
        float v = g_h2[(size_t)n * 128 + t] * sc + sh;
        acc += (v > 0.f ? v : expm1f(v));
    }
    __shared__ float p[128], hm[64];
    float cnt = fmaxf((float)(end - beg), 1.f);
    p[t] = acc / cnt;
    __syncthreads();
    if (t < 64) {
        float a = b1[t];
        for (int k = 0; k < 128; ++k) a += p[k] * W1[k * 64 + t];
        hm[t] = a > 0.f ? a : expm1f(a);
    }
    __syncthreads();
    if (t < 12) {
        float o = b2[t];
        for (int k = 0; k < 64; ++k) o += hm[k] * W2[k * 12 + t];
        out[g * 12 + t] = o;
    }
}

// ---------------- launch ----------------
extern "C" void kernel_launch(void* const* d_in, const int* in_sizes, int n_in,
                              void* d_out, int out_size, void* d_ws, size_t ws_size,
                              hipStream_t stream) {
    const float* x     = (const float*)d_in[0];
    const int*   ei    = (const int*)d_in[1];
    const float* ea    = (const float*)d_in[2];
    const int*   batch = (const int*)d_in[3];
    const float* Wl1   = (const float*)d_in[4];
    const float* bl1   = (const float*)d_in[5];
    const float* Wr1   = (const float*)d_in[6];
    const float* br1   = (const float*)d_in[7];
    const float* We1   = (const float*)d_in[8];
    const float* att1  = (const float*)d_in[9];
    const float* bias1 = (const float*)d_in[10];
    const float* g1    = (const float*)d_in[11];
    const float* be1   = (const float*)d_in[12];
    const float* Wl2   = (const float*)d_in[13];
    const float* bl2   = (const float*)d_in[14];
    const float* Wr2   = (const float*)d_in[15];
    const float* br2   = (const float*)d_in[16];
    const float* We2   = (const float*)d_in[17];
    const float* att2  = (const float*)d_in[18];
    const float* bias2 = (const float*)d_in[19];
    const float* g2    = (const float*)d_in[20];
    const float* be2   = (const float*)d_in[21];
    const float* Wlin1 = (const float*)d_in[22];
    const float* blin1 = (const float*)d_in[23];
    const float* Wlin2 = (const float*)d_in[24];
    const float* blin2 = (const float*)d_in[25];
    float* out = (float*)d_out;
    const int* src = ei;
    const int* dst = ei + NE_;

    // CSR build (g_deg is zero at entry: BSS at load, re-zeroed by k_scan3 each launch)
    k_hist<<<2500, 256, 0, stream>>>(dst);
    k_scan1<<<NBLK_SCAN, 256, 0, stream>>>();
    k_scan2<<<1, 256, 0, stream>>>();
    k_scan3<<<NBLK_SCAN, 256, 0, stream>>>();
    k_scatter<<<2500, 256, 0, stream>>>(src, dst, ea);

    // layer 1 (xl/xr recomputed in-kernel; no xform pass)
    k_wconv<<<256, 256, 0, stream>>>(Wl2, Wr2);    // independent; early
    k_gat<1><<<NN_, 64, 0, stream>>>(att1, We1, bias1, x, Wl1, bl1, Wr1, br1);
    k_bn_stats<256><<<NBP, 256, 0, stream>>>();
    k_bn_reduce<256><<<NB2, 256, 0, stream>>>();
    k_bn_finalize<256><<<1, 256, 0, stream>>>(g1, be1);
    k_bn_apply1<<<2048, 256, 0, stream>>>();

    // layer 2 projections: MFMA bf16 dual-GEMM
    k_gemm2<<<dim3(313, 4), 256, 0, stream>>>(bl2, br2);

    // layer 2
    k_gat<2><<<NN_, 64, 0, stream>>>(att2, We2, bias2, x, Wl1, bl1, Wr1, br1);
    k_bn_stats<128><<<NBP, 128, 0, stream>>>();
    k_bn_reduce<128><<<NB2, 128, 0, stream>>>();

    // fused: BN-finalize(l2) + pool(BN+ELU) + head
    k_tail<<<NG_, 128, 0, stream>>>(g2, be2, batch, Wlin1, blin1, Wlin2, blin2, out);
}

// Round 16
// 404.454 us; speedup vs baseline: 1.0487x; 1.0487x over previous
//
#include <hip/hip_runtime.h>
#include <math.h>

#define NN_ 40000
#define NE_ 640000
#define NG_ 400
#define NBLK_SCAN 157    // ceil(40000/256)
#define NBP 1024         // stage-1 partial blocks for BN stats (atomic-free)
#define NB2 32           // stage-2 reduced partials

typedef unsigned short ushort_t;
typedef __attribute__((ext_vector_type(8))) short bf16x8;
typedef __attribute__((ext_vector_type(4))) float f32x4;

// ---------------- device scratch ----------------
// NOTE: __device__ globals must NEVER be passed as kernel arguments from host
// (host sees shadow symbol address -> GPU fault). Always bind inside kernels.
__device__ int    g_deg[NN_];        // zero at load (BSS); re-zeroed by k_scan3 each launch
__device__ int    g_rowstart[NN_ + 1];
__device__ int    g_cursor[NN_];
__device__ int    g_srccsr[NE_];
__device__ float4 g_eacsr[NE_];
__device__ int    g_bsum[NBLK_SCAN], g_boff[NBLK_SCAN];
__device__ ushort_t g_xl2[(size_t)NN_ * 256];
__device__ ushort_t g_xr2[(size_t)NN_ * 256];
__device__ float  g_h1[(size_t)NN_ * 256];
__device__ ushort_t g_h1b[(size_t)NN_ * 256];   // bf16 h1 (post BN+ELU) for MFMA GEMM
__device__ ushort_t g_wl2t[256 * 256];          // Wl2^T bf16 [n][k]
__device__ ushort_t g_wr2t[256 * 256];          // Wr2^T bf16 [n][k]
__device__ float  g_h2[(size_t)NN_ * 128];      // raw (pre-BN) layer-2 output
__device__ float  g_part_s[NBP][256];           // BN stage-1 partials
__device__ float  g_part_q[NBP][256];
__device__ float  g_p2_s[NB2][256];             // BN stage-2 partials
__device__ float  g_p2_q[NB2][256];
__device__ float  g_scale[256], g_shift[256];

// bf16 helpers: arrays of ushort bf16, accessed pairwise via uint
__device__ __forceinline__ float bflo(unsigned int q) { return __uint_as_float(q << 16); }
__device__ __forceinline__ float bfhi(unsigned int q) { return __uint_as_float(q & 0xFFFF0000u); }
__device__ __forceinline__ unsigned int f2bf(float f) {
    unsigned int u = __float_as_uint(f);
    return (u + 0x7FFFu + ((u >> 16) & 1u)) >> 16;
}
__device__ __forceinline__ unsigned int pack2(float a, float b) {
    return f2bf(a) | (f2bf(b) << 16);
}

// ---------------- CSR build ----------------
__global__ void k_hist(const int* __restrict__ dst) {
    int e = blockIdx.x * blockDim.x + threadIdx.x;
    if (e < NE_) atomicAdd(&g_deg[dst[e]], 1);
}

__global__ void k_scan1() {
    __shared__ int sd[256];
    int b = blockIdx.x, t = threadIdx.x, i = b * 256 + t;
    int v = (i < NN_) ? g_deg[i] : 0;
    sd[t] = v;
    __syncthreads();
    for (int off = 1; off < 256; off <<= 1) {
        int tv = (t >= off) ? sd[t - off] : 0;
        __syncthreads();
        sd[t] += tv;
        __syncthreads();
    }
    if (i < NN_) g_rowstart[i] = sd[t] - v;   // block-local exclusive
    if (t == 255) g_bsum[b] = sd[255];
}

__global__ void k_scan2() {
    __shared__ int sd[256];
    int t = threadIdx.x;
    int v = (t < NBLK_SCAN) ? g_bsum[t] : 0;
    sd[t] = v;
    __syncthreads();
    for (int off = 1; off < 256; off <<= 1) {
        int tv = (t >= off) ? sd[t - off] : 0;
        __syncthreads();
        sd[t] += tv;
        __syncthreads();
    }
    if (t < NBLK_SCAN) g_boff[t] = sd[t] - v;
    if (t == 255) g_rowstart[NN_] = sd[255];
}

__global__ void k_scan3() {
    int i = blockIdx.x * blockDim.x + threadIdx.x;
    if (i < NN_) {
        int r = g_rowstart[i] + g_boff[i >> 8];
        g_rowstart[i] = r;
        g_cursor[i] = r;
        g_deg[i] = 0;   // restore invariant for next launch (k_scan1 already consumed)
    }
}

__global__ void k_scatter(const int* __restrict__ src, const int* __restrict__ dst,
                          const float* __restrict__ ea) {
    int e = blockIdx.x * blockDim.x + threadIdx.x;
    if (e < NE_) {
        int pos = atomicAdd(&g_cursor[dst[e]], 1);
        g_srccsr[pos] = src[e];
        g_eacsr[pos] = reinterpret_cast<const float4*>(ea)[e];
    }
}

// ---------------- fused GATv2 layer: flash-style, ONE WAVE (64 thr) per node ----
// r14 configuration (28 VGPR, ~70% occupancy): single-edge loop with 1-deep
// software pipeline. r15's unroll-2 doubled VGPR to 56 -> occupancy 39% ->
// latency-bound regression. Do NOT unroll this loop.
// LAYER 1: xl/xr recomputed on the fly from x (rank-2). LAYER 2: bf16 gather.
// Defer-max fast path is exact (see r9).
template <int LAYER>
__global__ void k_gat(const float* __restrict__ att, const float* __restrict__ We,
                      const float* __restrict__ bias, const float* __restrict__ x,
                      const float* __restrict__ Wl, const float* __restrict__ bl,
                      const float* __restrict__ Wr, const float* __restrict__ br) {
    constexpr int C = (LAYER == 1) ? 64 : 128;    // channels per head
    constexpr int GL = C / 4;                     // lanes per head group
    float* __restrict__ hout = (LAYER == 1) ? g_h1 : g_h2;

    int lane = threadIdx.x;      // 64 threads = 1 wave
    int n = blockIdx.x;
    int c4 = lane * 4;

    float a0 = att[c4], a1 = att[c4 + 1], a2c = att[c4 + 2], a3 = att[c4 + 3];
    float we00 = We[c4], we01 = We[c4 + 1], we02 = We[c4 + 2], we03 = We[c4 + 3];
    float we10 = We[256 + c4], we11 = We[256 + c4 + 1], we12 = We[256 + c4 + 2], we13 = We[256 + c4 + 3];
    float we20 = We[512 + c4], we21 = We[512 + c4 + 1], we22 = We[512 + c4 + 2], we23 = We[512 + c4 + 3];
    float we30 = We[768 + c4], we31 = We[768 + c4 + 1], we32 = We[768 + c4 + 2], we33 = We[768 + c4 + 3];

    // layer-1 source-transform columns (held in registers)
    float wl00 = 0.f, wl01 = 0.f, wl02 = 0.f, wl03 = 0.f;
    float wl10 = 0.f, wl11 = 0.f, wl12 = 0.f, wl13 = 0.f;
    float bl0 = 0.f, bl1 = 0.f, bl2 = 0.f, bl3 = 0.f;
    float xr0, xr1, xr2, xr3;
    if constexpr (LAYER == 1) {
        wl00 = Wl[c4 + 0]; wl01 = Wl[c4 + 1]; wl02 = Wl[c4 + 2]; wl03 = Wl[c4 + 3];
        wl10 = Wl[256 + c4 + 0]; wl11 = Wl[256 + c4 + 1]; wl12 = Wl[256 + c4 + 2]; wl13 = Wl[256 + c4 + 3];
        bl0 = bl[c4 + 0]; bl1 = bl[c4 + 1]; bl2 = bl[c4 + 2]; bl3 = bl[c4 + 3];
        float2 xn = *reinterpret_cast<const float2*>(x + 2 * n);
        xr0 = xn.x * Wr[c4 + 0] + xn.y * Wr[256 + c4 + 0] + br[c4 + 0];
        xr1 = xn.x * Wr[c4 + 1] + xn.y * Wr[256 + c4 + 1] + br[c4 + 1];
        xr2 = xn.x * Wr[c4 + 2] + xn.y * Wr[256 + c4 + 2] + br[c4 + 2];
        xr3 = xn.x * Wr[c4 + 3] + xn.y * Wr[256 + c4 + 3] + br[c4 + 3];
    } else {
        uint2 xq = *reinterpret_cast<const uint2*>(g_xr2 + (size_t)n * 256 + c4);
        xr0 = bflo(xq.x); xr1 = bfhi(xq.x); xr2 = bflo(xq.y); xr3 = bfhi(xq.y);
    }

    int s0 = g_rowstart[n];
    int d = g_rowstart[n + 1] - s0;

    float mrun = -INFINITY, den = 0.f;
    float acc0 = 0.f, acc1 = 0.f, acc2 = 0.f, acc3 = 0.f;

    // software pipeline state (1-deep)
    float4 eaA = make_float4(0.f, 0.f, 0.f, 0.f);
    float2 xsA = make_float2(0.f, 0.f);   // layer 1: source x
    uint2  rowA = make_uint2(0u, 0u);     // layer 2: gathered xl2 row
    if (d > 0) {
        int sA = g_srccsr[s0];
        eaA = g_eacsr[s0];
        if constexpr (LAYER == 1) xsA = *reinterpret_cast<const float2*>(x + 2 * sA);
        else rowA = *reinterpret_cast<const uint2*>(g_xl2 + (size_t)sA * 256 + c4);
    }
    for (int i = 0; i < d; ++i) {
        float4 eaB = eaA;
        float2 xsB = xsA;
        uint2  rowB = rowA;
        if (i + 1 < d) {
            int sB = g_srccsr[s0 + i + 1];
            eaB = g_eacsr[s0 + i + 1];
            if constexpr (LAYER == 1) xsB = *reinterpret_cast<const float2*>(x + 2 * sB);
            else rowB = *reinterpret_cast<const uint2*>(g_xl2 + (size_t)sB * 256 + c4);
        }
        float xl0, xl1, xl2, xl3;
        if constexpr (LAYER == 1) {
            xl0 = fmaf(xsA.y, wl10, fmaf(xsA.x, wl00, bl0));
            xl1 = fmaf(xsA.y, wl11, fmaf(xsA.x, wl01, bl1));
            xl2 = fmaf(xsA.y, wl12, fmaf(xsA.x, wl02, bl2));
            xl3 = fmaf(xsA.y, wl13, fmaf(xsA.x, wl03, bl3));
        } else {
            xl0 = bflo(rowA.x); xl1 = bfhi(rowA.x); xl2 = bflo(rowA.y); xl3 = bfhi(rowA.y);
        }
        float z0 = xl0 + xr0 + eaA.x * we00 + eaA.y * we10 + eaA.z * we20 + eaA.w * we30;
        float z1 = xl1 + xr1 + eaA.x * we01 + eaA.y * we11 + eaA.z * we21 + eaA.w * we31;
        float z2 = xl2 + xr2 + eaA.x * we02 + eaA.y * we12 + eaA.z * we22 + eaA.w * we32;
        float z3 = xl3 + xr3 + eaA.x * we03 + eaA.y * we13 + eaA.z * we23 + eaA.w * we33;
        z0 = fmaxf(z0, 0.2f * z0); z1 = fmaxf(z1, 0.2f * z1);
        z2 = fmaxf(z2, 0.2f * z2); z3 = fmaxf(z3, 0.2f * z3);
        float t = z0 * a0 + z1 * a1 + z2 * a2c + z3 * a3;
#pragma unroll
        for (int off = 1; off < GL; off <<= 1) t += __shfl_xor(t, off);
        if (__ballot(t > mrun) == 0ULL) {
            float w = __expf(t - mrun);
            den += w;
            acc0 = fmaf(w, xl0, acc0);
            acc1 = fmaf(w, xl1, acc1);
            acc2 = fmaf(w, xl2, acc2);
            acc3 = fmaf(w, xl3, acc3);
        } else {
            float mnew = fmaxf(mrun, t);
            float scl = __expf(mrun - mnew);
            float w = __expf(t - mnew);
            den = den * scl + w;
            acc0 = acc0 * scl + w * xl0;
            acc1 = acc1 * scl + w * xl1;
            acc2 = acc2 * scl + w * xl2;
            acc3 = acc3 * scl + w * xl3;
            mrun = mnew;
        }
        eaA = eaB; xsA = xsB; rowA = rowB;
    }
    float inv = 1.f / (den + 1e-16f);
    if constexpr (LAYER == 1) {
        float4 o = make_float4(acc0 * inv + bias[c4 + 0], acc1 * inv + bias[c4 + 1],
                               acc2 * inv + bias[c4 + 2], acc3 * inv + bias[c4 + 3]);
        *reinterpret_cast<float4*>(hout + (size_t)n * 256 + c4) = o;
    } else {
        float v0 = acc0 * inv, v1 = acc1 * inv, v2 = acc2 * inv, v3 = acc3 * inv;
        float u0 = __shfl_xor(v0, 32), u1 = __shfl_xor(v1, 32);
        float u2 = __shfl_xor(v2, 32), u3 = __shfl_xor(v3, 32);
        if (lane < 32) {
            float4 o = make_float4(0.5f * (v0 + u0) + bias[c4 + 0],
                                   0.5f * (v1 + u1) + bias[c4 + 1],
                                   0.5f * (v2 + u2) + bias[c4 + 2],
                                   0.5f * (v3 + u3) + bias[c4 + 3]);
            *reinterpret_cast<float4*>(hout + (size_t)n * 128 + c4) = o;
        }
    }
}

// ---------------- batchnorm: atomic-free three-level reduction ----------------
template <int C>
__global__ void k_bn_stats() {
    const float* h = (C == 256) ? (const float*)g_h1 : (const float*)g_h2;
    int c = threadIdx.x;
    float s = 0.f, ss = 0.f;
    for (int r = blockIdx.x; r < NN_; r += NBP) {
        float v = h[(size_t)r * C + c];
        s += v; ss += v * v;
    }
    g_part_s[blockIdx.x][c] = s;
    g_part_q[blockIdx.x][c] = ss;
}

template <int C>
__global__ void k_bn_reduce() {
    int c = threadIdx.x;
    int b = blockIdx.x;
    float s = 0.f, ss = 0.f;
    for (int p = b; p < NBP; p += NB2) {
        s += g_part_s[p][c];
        ss += g_part_q[p][c];
    }
    g_p2_s[b][c] = s;
    g_p2_q[b][c] = ss;
}

template <int C>
__global__ void k_bn_finalize(const float* __restrict__ g, const float* __restrict__ b) {
    int c = threadIdx.x;
    float s = 0.f, ss = 0.f;
#pragma unroll
    for (int p = 0; p < NB2; ++p) {
        s += g_p2_s[p][c];
        ss += g_p2_q[p][c];
    }
    float mu = s / (float)NN_;
    float var = ss / (float)NN_ - mu * mu;
    float sc = g[c] * rsqrtf(var + 1e-5f);
    g_scale[c] = sc;
    g_shift[c] = b[c] - mu * sc;
}

// BN+ELU for layer1, emitting bf16 g_h1b (feeds MFMA GEMM); vectorized 8-wide
__global__ void k_bn_apply1() {
    int i = blockIdx.x * blockDim.x + threadIdx.x;
    int stride = gridDim.x * blockDim.x;
    for (int j8 = i; j8 < NN_ * 32; j8 += stride) {
        size_t base = (size_t)j8 * 8;
        int c0 = (int)(base & 255);
        float4 v0 = *reinterpret_cast<const float4*>(g_h1 + base);
        float4 v1 = *reinterpret_cast<const float4*>(g_h1 + base + 4);
        float e[8];
        e[0] = v0.x * g_scale[c0 + 0] + g_shift[c0 + 0];
        e[1] = v0.y * g_scale[c0 + 1] + g_shift[c0 + 1];
        e[2] = v0.z * g_scale[c0 + 2] + g_shift[c0 + 2];
        e[3] = v0.w * g_scale[c0 + 3] + g_shift[c0 + 3];
        e[4] = v1.x * g_scale[c0 + 4] + g_shift[c0 + 4];
        e[5] = v1.y * g_scale[c0 + 5] + g_shift[c0 + 5];
        e[6] = v1.z * g_scale[c0 + 6] + g_shift[c0 + 6];
        e[7] = v1.w * g_scale[c0 + 7] + g_shift[c0 + 7];
#pragma unroll
        for (int q = 0; q < 8; ++q) e[q] = e[q] > 0.f ? e[q] : expm1f(e[q]);
        uint4 o = make_uint4(pack2(e[0], e[1]), pack2(e[2], e[3]),
                             pack2(e[4], e[5]), pack2(e[6], e[7]));
        *reinterpret_cast<uint4*>(g_h1b + base) = o;
    }
}

// ---------------- weight convert+transpose: W[k][n] fp32 -> Wt[n][k] bf16 --------
__global__ void k_wconv(const float* __restrict__ Wl, const float* __restrict__ Wr) {
    int n = blockIdx.x, k = threadIdx.x;   // 256 x 256
    g_wl2t[n * 256 + k] = (ushort_t)f2bf(Wl[(size_t)k * 256 + n]);
    g_wr2t[n * 256 + k] = (ushort_t)f2bf(Wr[(size_t)k * 256 + n]);
}

// ---------------- MFMA dual GEMM: h1b(40000x256,bf16) @ {Wl2,Wr2} -> xl2/xr2 ----
__global__ __launch_bounds__(256) void k_gemm2(const float* __restrict__ bl,
                                               const float* __restrict__ br) {
    __shared__ ushort_t As[128][40];
    __shared__ ushort_t Bs[2][64][40];
    int tid = threadIdx.x;
    int w = tid >> 6, lane = tid & 63;
    int m0 = blockIdx.x * 128, n0 = blockIdx.y * 64;

    f32x4 acc[2][4][2] = {};

    for (int k0 = 0; k0 < 256; k0 += 32) {
#pragma unroll
        for (int c = tid; c < 512; c += 256) {
            int row = c >> 2, seg = c & 3;
            int gr = m0 + row; gr = gr < NN_ ? gr : NN_ - 1;
            uint4 v = *reinterpret_cast<const uint4*>(g_h1b + (size_t)gr * 256 + k0 + seg * 8);
            *reinterpret_cast<uint4*>(&As[row][seg * 8]) = v;
        }
        {
            int row = tid >> 2, seg = tid & 3;
            uint4 v0 = *reinterpret_cast<const uint4*>(g_wl2t + (size_t)(n0 + row) * 256 + k0 + seg * 8);
            *reinterpret_cast<uint4*>(&Bs[0][row][seg * 8]) = v0;
            uint4 v1 = *reinterpret_cast<const uint4*>(g_wr2t + (size_t)(n0 + row) * 256 + k0 + seg * 8);
            *reinterpret_cast<uint4*>(&Bs[1][row][seg * 8]) = v1;
        }
        __syncthreads();
        int kb = (lane >> 4) * 8;
        bf16x8 a0 = *reinterpret_cast<const bf16x8*>(&As[w * 32 + (lane & 15)][kb]);
        bf16x8 a1 = *reinterpret_cast<const bf16x8*>(&As[w * 32 + 16 + (lane & 15)][kb]);
        bf16x8 b[4][2];
#pragma unroll
        for (int ni = 0; ni < 4; ++ni) {
            b[ni][0] = *reinterpret_cast<const bf16x8*>(&Bs[0][ni * 16 + (lane & 15)][kb]);
            b[ni][1] = *reinterpret_cast<const bf16x8*>(&Bs[1][ni * 16 + (lane & 15)][kb]);
        }
#pragma unroll
        for (int ni = 0; ni < 4; ++ni) {
#pragma unroll
            for (int mat = 0; mat < 2; ++mat) {
                acc[0][ni][mat] = __builtin_amdgcn_mfma_f32_16x16x32_bf16(a0, b[ni][mat], acc[0][ni][mat], 0, 0, 0);
                acc[1][ni][mat] = __builtin_amdgcn_mfma_f32_16x16x32_bf16(a1, b[ni][mat], acc[1][ni][mat], 0, 0, 0);
            }
        }
        __syncthreads();
    }
#pragma unroll
    for (int mat = 0; mat < 2; ++mat) {
        const float* bb = mat ? br : bl;
        ushort_t* outp = mat ? g_xr2 : g_xl2;
#pragma unroll
        for (int ni = 0; ni < 4; ++ni) {
            int gcol = n0 + ni * 16 + (lane & 15);
            float bv = bb[gcol];
#pragma unroll
            for (int mi = 0; mi < 2; ++mi) {
#pragma unroll
                for (int r = 0; r < 4; ++r) {
                    int grow = m0 + w * 32 + mi * 16 + (lane >> 4) * 4 + r;
                    if (grow < NN_)
                        outp[(size_t)grow * 256 + gcol] = (ushort_t)f2bf(acc[mi][ni][mat][r] + bv);
                }
            }
        }
    }
}

// ---------------- fused tail: BN-finalize(128) + mean-pool(BN+ELU) + MLP head ----
__global__ void k_tail(const float* __restrict__ g2, const float* __restrict__ be2,
                       const int* __restrict__ batch,
                       const float* __restrict__ W1, const float* __restrict__ b1,
                       const float* __restrict__ W2, const float* __restrict__ b2,
                       float* __restrict__ out) {
    int g = blockIdx.x, t = threadIdx.x;  // 128 threads
    float s = 0.f, ss = 0.f;
#pragma unroll
    for (int p = 0; p < NB2; ++p) {
        s += g_p2_s[p][t];
        ss += g_p2_q[p][t];
    }
    float mu = s / (float)NN_;
    float var = ss / (float)NN_ - mu * mu;
    float sc = g2[t] * rsqrtf(var + 1e-5f);
    float sh = be2[t] - mu * sc;
    __shared__ int sbeg, send;
    if (t == 0) {
        int lo = 0, hi = NN_;
        while (lo < hi) { int mid = (lo + hi) >> 1; if (batch[mid] < g) lo = mid + 1; else hi = mid; }
        sbeg = lo;
    }
    if (t == 1) {
        int lo = 0, hi = NN_;
        while (lo < hi) { int mid = (lo + hi) >> 1; if (batch[mid] <= g) lo = mid + 1; else hi = mid; }
        send = lo;
    }
    __syncthreads();
    int beg = sbeg, end = send;
    float acc = 0.f;
    for (int n = beg; n < end; ++n) {
        float v = g_h2[(size_t)n * 128 + t] * sc + sh;
        acc += (v > 0.f ? v : expm1f(v));
    }
    __shared__ float p[128], hm[64];
    float cnt = fmaxf((float)(end - beg), 1.f);
    p[t] = acc / cnt;
    __syncthreads();
    if (t < 64) {
        float a = b1[t];
        for (int k = 0; k < 128; ++k) a += p[k] * W1[k * 64 + t];
        hm[t] = a > 0.f ? a : expm1f(a);
    }
    __syncthreads();
    if (t < 12) {
        float o = b2[t];
        for (int k = 0; k < 64; ++k) o += hm[k] * W2[k * 12 + t];
        out[g * 12 + t] = o;
    }
}

// ---------------- launch ----------------
extern "C" void kernel_launch(void* const* d_in, const int* in_sizes, int n_in,
                              void* d_out, int out_size, void* d_ws, size_t ws_size,
                              hipStream_t stream) {
    const float* x     = (const float*)d_in[0];
    const int*   ei    = (const int*)d_in[1];
    const float* ea    = (const float*)d_in[2];
    const int*   batch = (const int*)d_in[3];
    const float* Wl1   = (const float*)d_in[4];
    const float* bl1   = (const float*)d_in[5];
    const float* Wr1   = (const float*)d_in[6];
    const float* br1   = (const float*)d_in[7];
    const float* We1   = (const float*)d_in[8];
    const float* att1  = (const float*)d_in[9];
    const float* bias1 = (const float*)d_in[10];
    const float* g1    = (const float*)d_in[11];
    const float* be1   = (const float*)d_in[12];
    const float* Wl2   = (const float*)d_in[13];
    const float* bl2   = (const float*)d_in[14];
    const float* Wr2   = (const float*)d_in[15];
    const float* br2   = (const float*)d_in[16];
    const float* We2   = (const float*)d_in[17];
    const float* att2  = (const float*)d_in[18];
    const float* bias2 = (const float*)d_in[19];
    const float* g2    = (const float*)d_in[20];
    const float* be2   = (const float*)d_in[21];
    const float* Wlin1 = (const float*)d_in[22];
    const float* blin1 = (const float*)d_in[23];
    const float* Wlin2 = (const float*)d_in[24];
    const float* blin2 = (const float*)d_in[25];
    float* out = (float*)d_out;
    const int* src = ei;
    const int* dst = ei + NE_;

    // CSR build (g_deg is zero at entry: BSS at load, re-zeroed by k_scan3 each launch)
    k_hist<<<2500, 256, 0, stream>>>(dst);
    k_scan1<<<NBLK_SCAN, 256, 0, stream>>>();
    k_scan2<<<1, 256, 0, stream>>>();
    k_scan3<<<NBLK_SCAN, 256, 0, stream>>>();
    k_scatter<<<2500, 256, 0, stream>>>(src, dst, ea);

    // layer 1 (xl/xr recomputed in-kernel; no xform pass)
    k_wconv<<<256, 256, 0, stream>>>(Wl2, Wr2);    // independent; early
    k_gat<1><<<NN_, 64, 0, stream>>>(att1, We1, bias1, x, Wl1, bl1, Wr1, br1);
    k_bn_stats<256><<<NBP, 256, 0, stream>>>();
    k_bn_reduce<256><<<NB2, 256, 0, stream>>>();
    k_bn_finalize<256><<<1, 256, 0, stream>>>(g1, be1);
    k_bn_apply1<<<2048, 256, 0, stream>>>();

    // layer 2 projections: MFMA bf16 dual-GEMM
    k_gemm2<<<dim3(313, 4), 256, 0, stream>>>(bl2, br2);

    // layer 2
    k_gat<2><<<NN_, 64, 0, stream>>>(att2, We2, bias2, x, Wl1, bl1, Wr1, br1);
    k_bn_stats<128><<<NBP, 128, 0, stream>>>();
    k_bn_reduce<128><<<NB2, 128, 0, stream>>>();

    // fused: BN-finalize(l2) + pool(BN+ELU) + head
    k_tail<<<NG_, 128, 0, stream>>>(g2, be2, batch, Wlin1, blin1, Wlin2, blin2, out);
}